// Round 4
// baseline (3615.343 us; speedup 1.0000x reference)
//
#include <hip/hip_runtime.h>
#include <hip/hip_bf16.h>
#include <hip/hip_fp16.h>
#include <stdint.h>

// ============================================================================
// LSTMEncoder (3-layer Keras LSTM, per-gate input dropout 0.6, threefry RNG)
//   L0: x[256,1024,128] -> h0 ; L1: h0 -> h1 ; L2: h1 -> h_last[256,64] (f32)
// Round 4: recurrence rewrite (was LDS-broadcast-bound: 32 uniform b128/lane
// x 8 waves ~ 2560 cyc/step == measured 2580).
//   rec2: f16 h + v_dot2_f32_f16, all 4 gates per thread (no z exchange),
//         in-wave K-split (shfl_xor 32 combine), double-buffered h (1 barrier),
//         depth-2 global z prefetch. Target ~430 cyc/step.
//   gemm: epilogue now stores Z gate-interleaved [t][u*4+g] (rec loads 1x b64).
// Workspace: masks(1.5MB) + z_in f16(256MB) + h0,h1 f16(64MB ea)
// ============================================================================

#define MODE_F32  0
#define MODE_F16  2

typedef _Float16 h2v __attribute__((ext_vector_type(2)));

__device__ __forceinline__ float dot2f(h2v a, h2v b, float c){
#if __has_builtin(__builtin_amdgcn_fdot2)
  return __builtin_amdgcn_fdot2(a, b, c, false);
#else
  return fmaf((float)a.x, (float)b.x, fmaf((float)a.y, (float)b.y, c));
#endif
}

__device__ __forceinline__ h2v u32_h2(uint32_t u){
  union { uint32_t u; h2v h; } cv; cv.u = u; return cv.h;
}

// ---------------- dtype helpers ----------------
template<int M>
__device__ __forceinline__ void cvt8(const void* p, size_t i, float* o){
  if constexpr (M == MODE_F32){
    const float* f = (const float*)p + i;
    float4 a = *(const float4*)f;
    float4 b = *(const float4*)(f + 4);
    o[0]=a.x; o[1]=a.y; o[2]=a.z; o[3]=a.w;
    o[4]=b.x; o[5]=b.y; o[6]=b.z; o[7]=b.w;
  } else {
    uint4 r = *(const uint4*)((const uint16_t*)p + i);
    uint32_t hw[4] = {r.x, r.y, r.z, r.w};
    #pragma unroll
    for (int q=0;q<4;q++){
      __half_raw lo; lo.x = (unsigned short)(hw[q] & 0xffffu);
      __half_raw hi; hi.x = (unsigned short)(hw[q] >> 16);
      o[2*q]   = __half2float(__half(lo));
      o[2*q+1] = __half2float(__half(hi));
    }
  }
}

// ---------------- K2: JAX threefry2x32 (partitionable) masks ----------------
__device__ __forceinline__ void tf2x32(uint32_t k0, uint32_t k1,
                                       uint32_t& x0, uint32_t& x1){
  uint32_t ks2 = k0 ^ k1 ^ 0x1BD11BDAu;
  x0 += k0; x1 += k1;
#define TF_R(r) { x0 += x1; x1 = (x1<<r)|(x1>>(32-r)); x1 ^= x0; }
  TF_R(13) TF_R(15) TF_R(26) TF_R(6)  x0 += k1;  x1 += ks2 + 1u;
  TF_R(17) TF_R(29) TF_R(16) TF_R(24) x0 += ks2; x1 += k0  + 2u;
  TF_R(13) TF_R(15) TF_R(26) TF_R(6)  x0 += k0;  x1 += k1  + 3u;
  TF_R(17) TF_R(29) TF_R(16) TF_R(24) x0 += k1;  x1 += ks2 + 4u;
  TF_R(13) TF_R(15) TF_R(26) TF_R(6)  x0 += ks2; x1 += k0  + 5u;
#undef TF_R
}

__device__ __forceinline__ float bern_mask(uint32_t bits){
  float u = __uint_as_float((bits >> 9) | 0x3f800000u) - 1.0f;
  return (u < 0.4f) ? 2.5f : 0.0f;
}

__global__ void mask_kernel(float* __restrict__ masks){
  int gid = blockIdx.x * 256 + threadIdx.x;     // [0, 3*131072)
  int layer = gid >> 17;
  uint32_t i = (uint32_t)(gid & 131071);
  uint32_t k0 = 0u, k1 = (uint32_t)layer;
  tf2x32(0u, 4347u, k0, k1);                    // foldlike split
  uint32_t x0 = 0u, x1 = i;
  tf2x32(k0, k1, x0, x1);                       // partitionable bits
  masks[gid] = bern_mask(x0 ^ x1);
}

// ---------------- K3: input-projection GEMM ----------------
// A[262144][128] (dtype AM), W f32 [128][4*NT], per-gate mask on A rows.
// Z f16 [262144][4*NT], gate-interleaved: Z[row][n*4+gate].
template<int NT, int AM>
__global__ __launch_bounds__(256) void gemm_zin(
    const void*  __restrict__ A,
    const float* __restrict__ W,
    const float* __restrict__ bias,
    const float* __restrict__ maskL,   // this layer's masks [4][256][128]
    __half* __restrict__ Z)
{
  constexpr int WCOLS = 4*NT;
  constexpr int CT = NT/16;            // cols per thread (8 or 4)
  __shared__ float As[128][33];
  __shared__ float Ws[32][NT+4];
  const int tid  = threadIdx.x;
  const int r0   = blockIdx.x * 128;
  const int gate = blockIdx.y;
  const int bb   = blockIdx.x >> 3;
  const float* mrow = maskL + gate*32768 + bb*128;
  const int tr = tid >> 4, tc = tid & 15;

  float acc[8][CT];
  #pragma unroll
  for (int i=0;i<8;i++)
    #pragma unroll
    for (int j=0;j<CT;j++) acc[i][j] = 0.f;

  for (int kc=0; kc<4; ++kc){
    #pragma unroll
    for (int vv=0; vv<2; ++vv){
      int v = tid + 256*vv;
      int r = v >> 2;
      int d = (v & 3) << 3;
      float av[8];
      cvt8<AM>(A, (size_t)(r0 + r)*128 + kc*32 + d, av);
      const float* mp = mrow + kc*32 + d;
      float4 m0 = *(const float4*)mp;
      float4 m1 = *(const float4*)(mp + 4);
      float* dst = &As[r][d];
      dst[0]=av[0]*m0.x; dst[1]=av[1]*m0.y; dst[2]=av[2]*m0.z; dst[3]=av[3]*m0.w;
      dst[4]=av[4]*m1.x; dst[5]=av[5]*m1.y; dst[6]=av[6]*m1.z; dst[7]=av[7]*m1.w;
    }
    constexpr int WV = (32*NT)/(256*8);
    #pragma unroll
    for (int vv=0; vv<WV; ++vv){
      int v = tid + 256*vv;
      int f = v*8;
      int k = f / NT;
      int n = f - k*NT;
      float wv[8];
      cvt8<MODE_F32>(W, (size_t)(kc*32 + k)*WCOLS + gate*NT + n, wv);
      float* dst = &Ws[k][n];
      #pragma unroll
      for (int q=0;q<8;q++) dst[q] = wv[q];
    }
    __syncthreads();
    #pragma unroll 4
    for (int k=0;k<32;k++){
      float a[8];
      #pragma unroll
      for (int i=0;i<8;i++) a[i] = As[tr*8+i][k];
      float w[CT];
      const float4* wp = (const float4*)&Ws[k][tc*CT];
      float4 w0 = wp[0];
      w[0]=w0.x; w[1]=w0.y; w[2]=w0.z; w[3]=w0.w;
      if constexpr (CT == 8){
        float4 w1 = wp[1];
        w[4]=w1.x; w[5]=w1.y; w[6]=w1.z; w[7]=w1.w;
      }
      #pragma unroll
      for (int i=0;i<8;i++)
        #pragma unroll
        for (int j=0;j<CT;j++) acc[i][j] = fmaf(a[i], w[j], acc[i][j]);
    }
    __syncthreads();
  }
  // epilogue: + bias, store f16 gate-interleaved [row][n*4 + gate]
  float bj[CT];
  #pragma unroll
  for (int j=0;j<CT;j++) bj[j] = bias[gate*NT + tc*CT + j];
  #pragma unroll
  for (int i=0;i<8;i++){
    size_t rowbase = (size_t)(r0 + tr*8 + i)*WCOLS;
    #pragma unroll
    for (int j=0;j<CT;j++)
      Z[rowbase + (size_t)(tc*CT + j)*4 + gate] = __float2half(acc[i][j] + bj[j]);
  }
}

// ---------------- K4: recurrence v2 ----------------
__device__ __forceinline__ float sigf(float x){ return 1.0f/(1.0f + __expf(-x)); }
__device__ __forceinline__ float tanh_f(float x){ return 1.0f - 2.0f/(__expf(2.0f*x) + 1.0f); }

// 2U threads (U=128 -> 4 waves, U=64 -> 2 waves). lane l of wave w:
//   u = w*32 + (l&31)  (output unit), s = l>>5 (K-half).
// Thread computes 4 gate partial-dots over its K-half with v_dot2_f32_f16,
// combines with partner (l^32) via shfl_xor, computes gates redundantly.
// h double-buffered f16 in LDS -> ONE barrier per step.
template<int U, bool SEQ>
__global__ __launch_bounds__(2*U, 1) void rec2_kernel(
    const __half* __restrict__ Zin,     // [256][1024][U*4] gate-interleaved
    const float*  __restrict__ Wr,      // [U][4U]
    __half* __restrict__ Hseq,          // [256][1024][U]  (SEQ)
    float*  __restrict__ Hlast)         // [256][U]        (!SEQ)
{
  constexpr int C  = 4*U;       // z row length
  constexpr int NP = U/4;       // f16 pairs per K-half (U/2 d's)
  constexpr int NV = U/16;      // uint4 loads per K-half
  const int row = blockIdx.x;
  const int tid = threadIdx.x;
  const int l   = tid & 63;
  const int w   = tid >> 6;
  const int u   = w*32 + (l & 31);
  const int s   = l >> 5;
  const int d0  = s * (U/2);

  // recurrent weights, packed f16 pairs: wpk[g][j] = (Wr[d0+2j][gU+u], Wr[d0+2j+1][gU+u])
  h2v wpk[4][NP];
  #pragma unroll
  for (int g=0; g<4; ++g)
    #pragma unroll
    for (int j=0; j<NP; ++j){
      h2v t;
      t.x = (_Float16)Wr[(size_t)(d0 + 2*j    )*C + g*U + u];
      t.y = (_Float16)Wr[(size_t)(d0 + 2*j + 1)*C + g*U + u];
      wpk[g][j] = t;
    }

  __shared__ _Float16 hbuf[2][U];
  if (s == 0) hbuf[0][u] = (_Float16)0.0f;
  float cst = 0.0f;

  const __half* zb = Zin + (size_t)row*1024*C + (size_t)u*4;
  uint2 zA = *(const uint2*)(zb);          // t=0
  uint2 zB = *(const uint2*)(zb + C);      // t=1
  __syncthreads();

  #pragma unroll 1
  for (int t=0; t<1024; t += 2){
    #pragma unroll
    for (int half=0; half<2; ++half){
      const int tt = t + half;
      uint2 zcur = half ? zB : zA;
      // prefetch t+2 (tiny overrun past last row stays inside workspace)
      uint2 zn = *(const uint2*)(zb + (size_t)(tt+2 < 1024 ? tt+2 : tt)*C);
      if (half) zB = zn; else zA = zn;

      h2v zp0 = u32_h2(zcur.x);            // (z_i, z_f) from GEMM (+bias)
      h2v zp1 = u32_h2(zcur.y);            // (z_g, z_o)
      float a0 = (float)zp0.x * 0.5f;      // halve: partner shfl-add doubles
      float a1 = (float)zp0.y * 0.5f;      // the z term (both halves add it)
      float a2 = (float)zp1.x * 0.5f;
      float a3 = (float)zp1.y * 0.5f;

      const uint4* hv = (const uint4*)&hbuf[tt & 1][d0];
      #pragma unroll
      for (int q=0; q<NV; ++q){
        uint4 hq = hv[q];
        uint32_t hw[4] = {hq.x, hq.y, hq.z, hq.w};
        #pragma unroll
        for (int k=0; k<4; ++k){
          h2v hp = u32_h2(hw[k]);
          a0 = dot2f(hp, wpk[0][4*q+k], a0);
          a1 = dot2f(hp, wpk[1][4*q+k], a1);
          a2 = dot2f(hp, wpk[2][4*q+k], a2);
          a3 = dot2f(hp, wpk[3][4*q+k], a3);
        }
      }
      // combine K-halves (partner lane l^32); both sides get full sums
      float zi = a0 + __shfl_xor(a0, 32, 64);
      float zf = a1 + __shfl_xor(a1, 32, 64);
      float zg = a2 + __shfl_xor(a2, 32, 64);
      float zo = a3 + __shfl_xor(a3, 32, 64);

      float gi = sigf(zi), gf = sigf(zf), gg = tanh_f(zg), go = sigf(zo);
      cst = fmaf(gf, cst, gi*gg);
      float h = go * tanh_f(cst);

      if (s == 0){
        hbuf[(tt & 1) ^ 1][u] = (_Float16)h;
        if constexpr (SEQ)
          Hseq[((size_t)row*1024 + tt)*U + u] = __float2half(h);
        else
          if (tt == 1023) Hlast[(size_t)row*U + u] = h;
      }
      __syncthreads();
    }
  }
}

// ---------------- host launch ----------------
extern "C" void kernel_launch(void* const* d_in, const int* in_sizes, int n_in,
                              void* d_out, int out_size, void* d_ws, size_t ws_size,
                              hipStream_t stream)
{
  (void)in_sizes; (void)n_in; (void)out_size; (void)ws_size;
  const void*  x   = d_in[0];
  const float* Wk0 = (const float*)d_in[1];
  const float* Wr0 = (const float*)d_in[2];
  const float* b0  = (const float*)d_in[3];
  const float* Wk1 = (const float*)d_in[4];
  const float* Wr1 = (const float*)d_in[5];
  const float* b1  = (const float*)d_in[6];
  const float* Wko = (const float*)d_in[7];
  const float* Wro = (const float*)d_in[8];
  const float* bo  = (const float*)d_in[9];

  char* ws = (char*)d_ws;
  float*  masks = (float*)(ws + 256);                           // 1.5 MB
  __half* zin   = (__half*)(ws + 256 + 3*131072*4);             // 256 MB
  __half* h0    = (__half*)((char*)zin + (size_t)262144*512*2); // 64 MB
  __half* h1    = h0 + (size_t)262144*128;                      // 64 MB
  float*  out   = (float*)d_out;

  mask_kernel<<<1536, 256, 0, stream>>>(masks);

  // layer 0 (A = x, f32)
  gemm_zin<128, MODE_F32><<<dim3(2048,4), 256, 0, stream>>>(x, Wk0, b0, masks, zin);
  rec2_kernel<128, true><<<256, 256, 0, stream>>>(zin, Wr0, h0, nullptr);
  // layer 1 (A = h0, f16 ours)
  gemm_zin<128, MODE_F16><<<dim3(2048,4), 256, 0, stream>>>(h0, Wk1, b1, masks + 131072, zin);
  rec2_kernel<128, true><<<256, 256, 0, stream>>>(zin, Wr1, h1, nullptr);
  // layer 2 (output, U=64, last state only, f32 out)
  gemm_zin<64, MODE_F16><<<dim3(2048,4), 256, 0, stream>>>(h1, Wko, bo, masks + 262144, zin);
  rec2_kernel<64, false><<<256, 128, 0, stream>>>(zin, Wro, nullptr, out);
}

// Round 5
// 2749.086 us; speedup vs baseline: 1.3151x; 1.3151x over previous
//
#include <hip/hip_runtime.h>
#include <hip/hip_bf16.h>
#include <hip/hip_fp16.h>
#include <stdint.h>

// ============================================================================
// LSTMEncoder (3-layer Keras LSTM, per-gate input dropout 0.6, threefry RNG)
//   L0: x[256,1024,128] -> h0 ; L1: h0 -> h1 ; L2: h1 -> h_last[256,64] (f32)
// Round 5: revert round-4 GEMM epilogue regression.
//   - Z back to PLANAR [row][g*U+u] + uint4 stores (round-4 gate-interleaved
//     scalar stores caused 4x write amplification: WRITE_SIZE 1.03GB vs 256MB,
//     GEMM 350 -> 850us).
//   - rec2 now loads 4 planar f16 gate scalars (coalesced 128B/wave/gate),
//     keeps f16 h + v_dot2, in-wave K-split, 1 barrier/step, depth-2 prefetch.
// Workspace: masks(1.5MB) + z_in f16(256MB) + h0,h1 f16(64MB ea)
// ============================================================================

#define MODE_F32  0
#define MODE_F16  2

typedef _Float16 h2v __attribute__((ext_vector_type(2)));

__device__ __forceinline__ float dot2f(h2v a, h2v b, float c){
#if __has_builtin(__builtin_amdgcn_fdot2)
  return __builtin_amdgcn_fdot2(a, b, c, false);
#else
  return fmaf((float)a.x, (float)b.x, fmaf((float)a.y, (float)b.y, c));
#endif
}

__device__ __forceinline__ h2v u32_h2(uint32_t u){
  union { uint32_t u; h2v h; } cv; cv.u = u; return cv.h;
}

__device__ __forceinline__ float h16f(uint16_t b){
  __half_raw hr; hr.x = b; return __half2float(__half(hr));
}

// ---------------- dtype helpers ----------------
template<int M>
__device__ __forceinline__ void cvt8(const void* p, size_t i, float* o){
  if constexpr (M == MODE_F32){
    const float* f = (const float*)p + i;
    float4 a = *(const float4*)f;
    float4 b = *(const float4*)(f + 4);
    o[0]=a.x; o[1]=a.y; o[2]=a.z; o[3]=a.w;
    o[4]=b.x; o[5]=b.y; o[6]=b.z; o[7]=b.w;
  } else {
    uint4 r = *(const uint4*)((const uint16_t*)p + i);
    uint32_t hw[4] = {r.x, r.y, r.z, r.w};
    #pragma unroll
    for (int q=0;q<4;q++){
      o[2*q]   = h16f((uint16_t)(hw[q] & 0xffffu));
      o[2*q+1] = h16f((uint16_t)(hw[q] >> 16));
    }
  }
}

// ---------------- K2: JAX threefry2x32 (partitionable) masks ----------------
__device__ __forceinline__ void tf2x32(uint32_t k0, uint32_t k1,
                                       uint32_t& x0, uint32_t& x1){
  uint32_t ks2 = k0 ^ k1 ^ 0x1BD11BDAu;
  x0 += k0; x1 += k1;
#define TF_R(r) { x0 += x1; x1 = (x1<<r)|(x1>>(32-r)); x1 ^= x0; }
  TF_R(13) TF_R(15) TF_R(26) TF_R(6)  x0 += k1;  x1 += ks2 + 1u;
  TF_R(17) TF_R(29) TF_R(16) TF_R(24) x0 += ks2; x1 += k0  + 2u;
  TF_R(13) TF_R(15) TF_R(26) TF_R(6)  x0 += k0;  x1 += k1  + 3u;
  TF_R(17) TF_R(29) TF_R(16) TF_R(24) x0 += k1;  x1 += ks2 + 4u;
  TF_R(13) TF_R(15) TF_R(26) TF_R(6)  x0 += ks2; x1 += k0  + 5u;
#undef TF_R
}

__device__ __forceinline__ float bern_mask(uint32_t bits){
  float u = __uint_as_float((bits >> 9) | 0x3f800000u) - 1.0f;
  return (u < 0.4f) ? 2.5f : 0.0f;
}

__global__ void mask_kernel(float* __restrict__ masks){
  int gid = blockIdx.x * 256 + threadIdx.x;     // [0, 3*131072)
  int layer = gid >> 17;
  uint32_t i = (uint32_t)(gid & 131071);
  uint32_t k0 = 0u, k1 = (uint32_t)layer;
  tf2x32(0u, 4347u, k0, k1);                    // foldlike split
  uint32_t x0 = 0u, x1 = i;
  tf2x32(k0, k1, x0, x1);                       // partitionable bits
  masks[gid] = bern_mask(x0 ^ x1);
}

// ---------------- K3: input-projection GEMM ----------------
// A[262144][128] (dtype AM), W f32 [128][4*NT], per-gate mask on A rows.
// Z f16 PLANAR [262144][4*NT]: Z[row][gate*NT + n]. uint4/uint2 stores.
template<int NT, int AM>
__global__ __launch_bounds__(256) void gemm_zin(
    const void*  __restrict__ A,
    const float* __restrict__ W,
    const float* __restrict__ bias,
    const float* __restrict__ maskL,   // this layer's masks [4][256][128]
    __half* __restrict__ Z)
{
  constexpr int WCOLS = 4*NT;
  constexpr int CT = NT/16;            // cols per thread (8 or 4)
  __shared__ float As[128][33];        // +1 pad: conflict-free column reads
  __shared__ float Ws[32][NT+4];
  const int tid  = threadIdx.x;
  const int r0   = blockIdx.x * 128;   // row tile (1024%128==0 -> single batch)
  const int gate = blockIdx.y;
  const int bb   = blockIdx.x >> 3;    // batch index
  const float* mrow = maskL + gate*32768 + bb*128;
  const int tr = tid >> 4, tc = tid & 15;

  float acc[8][CT];
  #pragma unroll
  for (int i=0;i<8;i++)
    #pragma unroll
    for (int j=0;j<CT;j++) acc[i][j] = 0.f;

  for (int kc=0; kc<4; ++kc){
    // stage A chunk [128 x 32], masked, f32
    #pragma unroll
    for (int vv=0; vv<2; ++vv){
      int v = tid + 256*vv;
      int r = v >> 2;
      int d = (v & 3) << 3;
      float av[8];
      cvt8<AM>(A, (size_t)(r0 + r)*128 + kc*32 + d, av);
      const float* mp = mrow + kc*32 + d;
      float4 m0 = *(const float4*)mp;
      float4 m1 = *(const float4*)(mp + 4);
      float* dst = &As[r][d];
      dst[0]=av[0]*m0.x; dst[1]=av[1]*m0.y; dst[2]=av[2]*m0.z; dst[3]=av[3]*m0.w;
      dst[4]=av[4]*m1.x; dst[5]=av[5]*m1.y; dst[6]=av[6]*m1.z; dst[7]=av[7]*m1.w;
    }
    // stage W chunk [32 x NT]
    constexpr int WV = (32*NT)/(256*8);
    #pragma unroll
    for (int vv=0; vv<WV; ++vv){
      int v = tid + 256*vv;
      int f = v*8;
      int k = f / NT;
      int n = f - k*NT;
      float wv[8];
      cvt8<MODE_F32>(W, (size_t)(kc*32 + k)*WCOLS + gate*NT + n, wv);
      float* dst = &Ws[k][n];
      #pragma unroll
      for (int q=0;q<8;q++) dst[q] = wv[q];
    }
    __syncthreads();
    #pragma unroll 4
    for (int k=0;k<32;k++){
      float a[8];
      #pragma unroll
      for (int i=0;i<8;i++) a[i] = As[tr*8+i][k];
      float w[CT];
      const float4* wp = (const float4*)&Ws[k][tc*CT];
      float4 w0 = wp[0];
      w[0]=w0.x; w[1]=w0.y; w[2]=w0.z; w[3]=w0.w;
      if constexpr (CT == 8){
        float4 w1 = wp[1];
        w[4]=w1.x; w[5]=w1.y; w[6]=w1.z; w[7]=w1.w;
      }
      #pragma unroll
      for (int i=0;i<8;i++)
        #pragma unroll
        for (int j=0;j<CT;j++) acc[i][j] = fmaf(a[i], w[j], acc[i][j]);
    }
    __syncthreads();
  }
  // epilogue: + bias, vectorized f16 store (planar)
  float bj[CT];
  #pragma unroll
  for (int j=0;j<CT;j++) bj[j] = bias[gate*NT + tc*CT + j];
  #pragma unroll
  for (int i=0;i<8;i++){
    union { __half h[8]; uint4 u4; uint2 u2; } pk;
    #pragma unroll
    for (int j=0;j<CT;j++) pk.h[j] = __float2half(acc[i][j] + bj[j]);
    size_t idx = (size_t)(r0 + tr*8 + i)*WCOLS + gate*NT + tc*CT;
    if constexpr (CT == 8) *(uint4*)(Z + idx) = pk.u4;
    else                   *(uint2*)(Z + idx) = pk.u2;
  }
}

// ---------------- K4: recurrence v2 (planar z loads) ----------------
__device__ __forceinline__ float sigf(float x){ return 1.0f/(1.0f + __expf(-x)); }
__device__ __forceinline__ float tanh_f(float x){ return 1.0f - 2.0f/(__expf(2.0f*x) + 1.0f); }

// 2U threads (U=128 -> 4 waves, U=64 -> 2 waves). lane l of wave w:
//   u = w*32 + (l&31)  (output unit), s = l>>5 (K-half).
// Thread computes 4 gate partial-dots over its K-half with v_dot2_f32_f16,
// combines with partner (l^32) via shfl_xor, computes gates redundantly.
// h double-buffered f16 in LDS -> ONE barrier per step. z planar, 4 scalar
// f16 loads/step (coalesced per gate), depth-2 prefetch.
template<int U, bool SEQ>
__global__ __launch_bounds__(2*U, 1) void rec2_kernel(
    const __half* __restrict__ Zin,     // [256][1024][4U] planar [g*U+u]
    const float*  __restrict__ Wr,      // [U][4U]
    __half* __restrict__ Hseq,          // [256][1024][U]  (SEQ)
    float*  __restrict__ Hlast)         // [256][U]        (!SEQ)
{
  constexpr int C  = 4*U;       // z row length
  constexpr int NP = U/4;       // f16 pairs per K-half (U/2 d's)
  constexpr int NV = U/16;      // uint4 loads per K-half
  const int row = blockIdx.x;
  const int tid = threadIdx.x;
  const int l   = tid & 63;
  const int w   = tid >> 6;
  const int u   = w*32 + (l & 31);
  const int s   = l >> 5;
  const int d0  = s * (U/2);

  // recurrent weights, packed f16 pairs: wpk[g][j] = (Wr[d0+2j][gU+u], Wr[d0+2j+1][gU+u])
  h2v wpk[4][NP];
  #pragma unroll
  for (int g=0; g<4; ++g)
    #pragma unroll
    for (int j=0; j<NP; ++j){
      h2v t;
      t.x = (_Float16)Wr[(size_t)(d0 + 2*j    )*C + g*U + u];
      t.y = (_Float16)Wr[(size_t)(d0 + 2*j + 1)*C + g*U + u];
      wpk[g][j] = t;
    }

  __shared__ _Float16 hbuf[2][U];
  if (s == 0) hbuf[0][u] = (_Float16)0.0f;
  float cst = 0.0f;

  const uint16_t* zb = (const uint16_t*)Zin + (size_t)row*1024*C + u;
  uint16_t zA[4], zB[4];
  #pragma unroll
  for (int g=0; g<4; ++g){
    zA[g] = zb[g*U];              // t=0
    zB[g] = zb[C + g*U];          // t=1
  }
  __syncthreads();

  #pragma unroll 1
  for (int t=0; t<1024; t += 2){
    #pragma unroll
    for (int half=0; half<2; ++half){
      const int tt = t + half;
      float a0, a1, a2, a3;
      {
        const uint16_t* zc = half ? zB : zA;
        a0 = h16f(zc[0]) * 0.5f;       // halve: partner shfl-add doubles
        a1 = h16f(zc[1]) * 0.5f;       // the z term (both halves add it)
        a2 = h16f(zc[2]) * 0.5f;
        a3 = h16f(zc[3]) * 0.5f;
      }
      // prefetch t+2 (clamped to stay in-bounds)
      {
        const int tn = (tt + 2 < 1024) ? tt + 2 : tt;
        const uint16_t* zp = zb + (size_t)tn*C;
        uint16_t* zd = half ? zB : zA;
        #pragma unroll
        for (int g=0; g<4; ++g) zd[g] = zp[g*U];
      }

      const uint4* hv = (const uint4*)&hbuf[tt & 1][d0];
      #pragma unroll
      for (int q=0; q<NV; ++q){
        uint4 hq = hv[q];
        uint32_t hw[4] = {hq.x, hq.y, hq.z, hq.w};
        #pragma unroll
        for (int k=0; k<4; ++k){
          h2v hp = u32_h2(hw[k]);
          a0 = dot2f(hp, wpk[0][4*q+k], a0);
          a1 = dot2f(hp, wpk[1][4*q+k], a1);
          a2 = dot2f(hp, wpk[2][4*q+k], a2);
          a3 = dot2f(hp, wpk[3][4*q+k], a3);
        }
      }
      // combine K-halves (partner lane l^32); both sides get full sums
      float zi = a0 + __shfl_xor(a0, 32, 64);
      float zf = a1 + __shfl_xor(a1, 32, 64);
      float zg = a2 + __shfl_xor(a2, 32, 64);
      float zo = a3 + __shfl_xor(a3, 32, 64);

      float gi = sigf(zi), gf = sigf(zf), gg = tanh_f(zg), go = sigf(zo);
      cst = fmaf(gf, cst, gi*gg);
      float h = go * tanh_f(cst);

      if (s == 0){
        hbuf[(tt & 1) ^ 1][u] = (_Float16)h;
        if constexpr (SEQ)
          Hseq[((size_t)row*1024 + tt)*U + u] = __float2half(h);
        else
          if (tt == 1023) Hlast[(size_t)row*U + u] = h;
      }
      __syncthreads();
    }
  }
}

// ---------------- host launch ----------------
extern "C" void kernel_launch(void* const* d_in, const int* in_sizes, int n_in,
                              void* d_out, int out_size, void* d_ws, size_t ws_size,
                              hipStream_t stream)
{
  (void)in_sizes; (void)n_in; (void)out_size; (void)ws_size;
  const void*  x   = d_in[0];
  const float* Wk0 = (const float*)d_in[1];
  const float* Wr0 = (const float*)d_in[2];
  const float* b0  = (const float*)d_in[3];
  const float* Wk1 = (const float*)d_in[4];
  const float* Wr1 = (const float*)d_in[5];
  const float* b1  = (const float*)d_in[6];
  const float* Wko = (const float*)d_in[7];
  const float* Wro = (const float*)d_in[8];
  const float* bo  = (const float*)d_in[9];

  char* ws = (char*)d_ws;
  float*  masks = (float*)(ws + 256);                           // 1.5 MB
  __half* zin   = (__half*)(ws + 256 + 3*131072*4);             // 256 MB
  __half* h0    = (__half*)((char*)zin + (size_t)262144*512*2); // 64 MB
  __half* h1    = h0 + (size_t)262144*128;                      // 64 MB
  float*  out   = (float*)d_out;

  mask_kernel<<<1536, 256, 0, stream>>>(masks);

  // layer 0 (A = x, f32)
  gemm_zin<128, MODE_F32><<<dim3(2048,4), 256, 0, stream>>>(x, Wk0, b0, masks, zin);
  rec2_kernel<128, true><<<256, 256, 0, stream>>>(zin, Wr0, h0, nullptr);
  // layer 1 (A = h0, f16 ours)
  gemm_zin<128, MODE_F16><<<dim3(2048,4), 256, 0, stream>>>(h0, Wk1, b1, masks + 131072, zin);
  rec2_kernel<128, true><<<256, 256, 0, stream>>>(zin, Wr1, h1, nullptr);
  // layer 2 (output, U=64, last state only, f32 out)
  gemm_zin<64, MODE_F16><<<dim3(2048,4), 256, 0, stream>>>(h1, Wko, bo, masks + 262144, zin);
  rec2_kernel<64, false><<<256, 128, 0, stream>>>(zin, Wro, nullptr, out);
}

// Round 6
// 2269.425 us; speedup vs baseline: 1.5931x; 1.2114x over previous
//
#include <hip/hip_runtime.h>
#include <hip/hip_bf16.h>
#include <hip/hip_fp16.h>
#include <stdint.h>

// ============================================================================
// LSTMEncoder (3-layer Keras LSTM, per-gate input dropout 0.6, threefry RNG)
//   L0: x[256,1024,128] -> h0 ; L1: h0 -> h1 ; L2: h1 -> h_last[256,64] (f32)
// Round 6: GEMM -> MFMA f16 (was f32 VALU, ~950us total; floor ~150us).
//   gemm_mfma: 128row x U-col tile (one gate per block), K=128 single-shot,
//     A,B staged f16 in LDS with XOR swizzle (k ^= (row&7)<<3, 16B units),
//     B transposed so A/B frags are contiguous ds_read_b128,
//     4 waves, mfma_f32_16x16x32_f16, f32 accum, bias in epilogue, f16 Z.
//   rec2 unchanged this round (700us/layer, 1640cyc/step, needs own redesign).
// Workspace: masks(1.5MB) + z_in f16(256MB) + h0,h1 f16(64MB ea)
// ============================================================================

#define MODE_F32  0
#define MODE_F16  2

typedef _Float16 h2v  __attribute__((ext_vector_type(2)));
typedef _Float16 f16x8 __attribute__((ext_vector_type(8)));
typedef float    f32x4 __attribute__((ext_vector_type(4)));

__device__ __forceinline__ float dot2f(h2v a, h2v b, float c){
#if __has_builtin(__builtin_amdgcn_fdot2)
  return __builtin_amdgcn_fdot2(a, b, c, false);
#else
  return fmaf((float)a.x, (float)b.x, fmaf((float)a.y, (float)b.y, c));
#endif
}

__device__ __forceinline__ h2v u32_h2(uint32_t u){
  union { uint32_t u; h2v h; } cv; cv.u = u; return cv.h;
}

__device__ __forceinline__ float h16f(uint16_t b){
  __half_raw hr; hr.x = b; return __half2float(__half(hr));
}

// ---------------- dtype helpers ----------------
template<int M>
__device__ __forceinline__ void cvt8(const void* p, size_t i, float* o){
  if constexpr (M == MODE_F32){
    const float* f = (const float*)p + i;
    float4 a = *(const float4*)f;
    float4 b = *(const float4*)(f + 4);
    o[0]=a.x; o[1]=a.y; o[2]=a.z; o[3]=a.w;
    o[4]=b.x; o[5]=b.y; o[6]=b.z; o[7]=b.w;
  } else {
    uint4 r = *(const uint4*)((const uint16_t*)p + i);
    uint32_t hw[4] = {r.x, r.y, r.z, r.w};
    #pragma unroll
    for (int q=0;q<4;q++){
      o[2*q]   = h16f((uint16_t)(hw[q] & 0xffffu));
      o[2*q+1] = h16f((uint16_t)(hw[q] >> 16));
    }
  }
}

// ---------------- K2: JAX threefry2x32 (partitionable) masks ----------------
__device__ __forceinline__ void tf2x32(uint32_t k0, uint32_t k1,
                                       uint32_t& x0, uint32_t& x1){
  uint32_t ks2 = k0 ^ k1 ^ 0x1BD11BDAu;
  x0 += k0; x1 += k1;
#define TF_R(r) { x0 += x1; x1 = (x1<<r)|(x1>>(32-r)); x1 ^= x0; }
  TF_R(13) TF_R(15) TF_R(26) TF_R(6)  x0 += k1;  x1 += ks2 + 1u;
  TF_R(17) TF_R(29) TF_R(16) TF_R(24) x0 += ks2; x1 += k0  + 2u;
  TF_R(13) TF_R(15) TF_R(26) TF_R(6)  x0 += k0;  x1 += k1  + 3u;
  TF_R(17) TF_R(29) TF_R(16) TF_R(24) x0 += k1;  x1 += ks2 + 4u;
  TF_R(13) TF_R(15) TF_R(26) TF_R(6)  x0 += ks2; x1 += k0  + 5u;
#undef TF_R
}

__device__ __forceinline__ float bern_mask(uint32_t bits){
  float u = __uint_as_float((bits >> 9) | 0x3f800000u) - 1.0f;
  return (u < 0.4f) ? 2.5f : 0.0f;
}

__global__ void mask_kernel(float* __restrict__ masks){
  int gid = blockIdx.x * 256 + threadIdx.x;     // [0, 3*131072)
  int layer = gid >> 17;
  uint32_t i = (uint32_t)(gid & 131071);
  uint32_t k0 = 0u, k1 = (uint32_t)layer;
  tf2x32(0u, 4347u, k0, k1);                    // foldlike split
  uint32_t x0 = 0u, x1 = i;
  tf2x32(k0, k1, x0, x1);                       // partitionable bits
  masks[gid] = bern_mask(x0 ^ x1);
}

// ---------------- K3: input-projection GEMM via MFMA f16 ----------------
// A[262144][128] (dtype AM), W f32 [128][4U], one gate per blockIdx.y.
// Z f16 PLANAR [262144][4U]: Z[row][gate*U + n].
// Tile: 128 rows x U cols, K=128 single shot. LDS f16, XOR-swizzled
// (16B-unit index XOR row&7) -> conflict-free b128 frag reads, 64KB max.
template<int U, int AM>
__global__ __launch_bounds__(256) void gemm_mfma(
    const void*  __restrict__ A,
    const float* __restrict__ W,
    const float* __restrict__ bias,
    const float* __restrict__ maskL,   // [4][256][128]
    __half* __restrict__ Z)
{
  constexpr int WC   = 4*U;
  constexpr int HALF = U/2;
  __shared__ _Float16 As [128][128];
  __shared__ _Float16 Bst[U  ][128];   // transposed: [col][k]
  const int tid  = threadIdx.x;
  const int r0   = blockIdx.x * 128;
  const int gate = blockIdx.y;
  const int bb   = blockIdx.x >> 3;    // batch (8 row-tiles per batch)
  const float* mrow = maskL + gate*32768 + bb*128;

  // ---- stage A: (x or h) * mask -> f16, swizzled ----
  {
    const int r  = tid >> 1;
    const int kh = (tid & 1) * 64;
    #pragma unroll
    for (int c=0;c<8;c++){
      int k0 = kh + c*8;
      float av[8]; cvt8<AM>(A, (size_t)(r0+r)*128 + k0, av);
      float4 m0 = *(const float4*)(mrow+k0);
      float4 m1 = *(const float4*)(mrow+k0+4);
      _Float16* dst = &As[r][k0 ^ ((r&7)<<3)];
      dst[0]=(_Float16)(av[0]*m0.x); dst[1]=(_Float16)(av[1]*m0.y);
      dst[2]=(_Float16)(av[2]*m0.z); dst[3]=(_Float16)(av[3]*m0.w);
      dst[4]=(_Float16)(av[4]*m1.x); dst[5]=(_Float16)(av[5]*m1.y);
      dst[6]=(_Float16)(av[6]*m1.z); dst[7]=(_Float16)(av[7]*m1.w);
    }
  }
  // ---- stage B: Wk gate slice, transposed + swizzled ----
  {
    const int d  = tid >> 1;
    const int ch = (tid & 1) * HALF;
    #pragma unroll
    for (int cc=0; cc<HALF/8; ++cc){
      int c0 = ch + cc*8;
      const float* wp = W + (size_t)d*WC + gate*U + c0;
      float4 w0 = *(const float4*)wp;
      float4 w1 = *(const float4*)(wp+4);
      float wv[8] = {w0.x,w0.y,w0.z,w0.w,w1.x,w1.y,w1.z,w1.w};
      #pragma unroll
      for (int q=0;q<8;q++){
        int c = c0 + q;
        Bst[c][d ^ ((c&7)<<3)] = (_Float16)wv[q];
      }
    }
  }
  __syncthreads();

  // ---- MFMA compute ----
  const int l  = tid & 63;
  const int w  = tid >> 6;
  const int lr = l & 15;
  const int kg = (l >> 4) * 8;
  constexpr int MF = (U==128) ? 4 : 2;         // m-frags per wave
  const int wr = (U==128) ? ((w>>1)*64) : (w*32);
  const int wc = (U==128) ? ((w&1)*64) : 0;

  f32x4 zz = {0.f,0.f,0.f,0.f};
  f32x4 acc[MF][4];
  #pragma unroll
  for (int m=0;m<MF;m++)
    #pragma unroll
    for (int n=0;n<4;n++) acc[m][n] = zz;

  #pragma unroll
  for (int ks=0; ks<4; ++ks){
    const int kb = ks*32 + kg;
    f16x8 af[MF], bf[4];
    #pragma unroll
    for (int m=0;m<MF;m++){
      int r = wr + m*16 + lr;
      af[m] = *(const f16x8*)&As[r][kb ^ ((r&7)<<3)];
    }
    #pragma unroll
    for (int n=0;n<4;n++){
      int c = wc + n*16 + lr;
      bf[n] = *(const f16x8*)&Bst[c][kb ^ ((c&7)<<3)];
    }
    #pragma unroll
    for (int m=0;m<MF;m++)
      #pragma unroll
      for (int n=0;n<4;n++)
        acc[m][n] = __builtin_amdgcn_mfma_f32_16x16x32_f16(af[m], bf[n], acc[m][n], 0, 0, 0);
  }

  // ---- epilogue: + bias, f16 planar stores ----
  // D layout (verified m89): col = lane&15, row = (lane>>4)*4 + reg
  const int crow = (l>>4)*4;
  float bv[4];
  #pragma unroll
  for (int n=0;n<4;n++) bv[n] = bias[gate*U + wc + n*16 + lr];
  #pragma unroll
  for (int m=0;m<MF;m++){
    #pragma unroll
    for (int n=0;n<4;n++){
      int cc = wc + n*16 + lr;
      #pragma unroll
      for (int j=0;j<4;j++){
        int rr = wr + m*16 + crow + j;
        Z[(size_t)(r0+rr)*WC + gate*U + cc] = __float2half(acc[m][n][j] + bv[n]);
      }
    }
  }
}

// ---------------- K4: recurrence v2 (planar z loads) ----------------
__device__ __forceinline__ float sigf(float x){ return 1.0f/(1.0f + __expf(-x)); }
__device__ __forceinline__ float tanh_f(float x){ return 1.0f - 2.0f/(__expf(2.0f*x) + 1.0f); }

template<int U, bool SEQ>
__global__ __launch_bounds__(2*U, 1) void rec2_kernel(
    const __half* __restrict__ Zin,     // [256][1024][4U] planar [g*U+u]
    const float*  __restrict__ Wr,      // [U][4U]
    __half* __restrict__ Hseq,          // [256][1024][U]  (SEQ)
    float*  __restrict__ Hlast)         // [256][U]        (!SEQ)
{
  constexpr int C  = 4*U;
  constexpr int NP = U/4;
  constexpr int NV = U/16;
  const int row = blockIdx.x;
  const int tid = threadIdx.x;
  const int l   = tid & 63;
  const int w   = tid >> 6;
  const int u   = w*32 + (l & 31);
  const int s   = l >> 5;
  const int d0  = s * (U/2);

  h2v wpk[4][NP];
  #pragma unroll
  for (int g=0; g<4; ++g)
    #pragma unroll
    for (int j=0; j<NP; ++j){
      h2v t;
      t.x = (_Float16)Wr[(size_t)(d0 + 2*j    )*C + g*U + u];
      t.y = (_Float16)Wr[(size_t)(d0 + 2*j + 1)*C + g*U + u];
      wpk[g][j] = t;
    }

  __shared__ _Float16 hbuf[2][U];
  if (s == 0) hbuf[0][u] = (_Float16)0.0f;
  float cst = 0.0f;

  const uint16_t* zb = (const uint16_t*)Zin + (size_t)row*1024*C + u;
  uint16_t zA[4], zB[4];
  #pragma unroll
  for (int g=0; g<4; ++g){
    zA[g] = zb[g*U];              // t=0
    zB[g] = zb[C + g*U];          // t=1
  }
  __syncthreads();

  #pragma unroll 1
  for (int t=0; t<1024; t += 2){
    #pragma unroll
    for (int half=0; half<2; ++half){
      const int tt = t + half;
      float a0, a1, a2, a3;
      {
        const uint16_t* zc = half ? zB : zA;
        a0 = h16f(zc[0]) * 0.5f;       // halve: partner shfl-add doubles
        a1 = h16f(zc[1]) * 0.5f;
        a2 = h16f(zc[2]) * 0.5f;
        a3 = h16f(zc[3]) * 0.5f;
      }
      {
        const int tn = (tt + 2 < 1024) ? tt + 2 : tt;
        const uint16_t* zp = zb + (size_t)tn*C;
        uint16_t* zd = half ? zB : zA;
        #pragma unroll
        for (int g=0; g<4; ++g) zd[g] = zp[g*U];
      }

      const uint4* hv = (const uint4*)&hbuf[tt & 1][d0];
      #pragma unroll
      for (int q=0; q<NV; ++q){
        uint4 hq = hv[q];
        uint32_t hw[4] = {hq.x, hq.y, hq.z, hq.w};
        #pragma unroll
        for (int k=0; k<4; ++k){
          h2v hp = u32_h2(hw[k]);
          a0 = dot2f(hp, wpk[0][4*q+k], a0);
          a1 = dot2f(hp, wpk[1][4*q+k], a1);
          a2 = dot2f(hp, wpk[2][4*q+k], a2);
          a3 = dot2f(hp, wpk[3][4*q+k], a3);
        }
      }
      float zi = a0 + __shfl_xor(a0, 32, 64);
      float zf = a1 + __shfl_xor(a1, 32, 64);
      float zg = a2 + __shfl_xor(a2, 32, 64);
      float zo = a3 + __shfl_xor(a3, 32, 64);

      float gi = sigf(zi), gf = sigf(zf), gg = tanh_f(zg), go = sigf(zo);
      cst = fmaf(gf, cst, gi*gg);
      float h = go * tanh_f(cst);

      if (s == 0){
        hbuf[(tt & 1) ^ 1][u] = (_Float16)h;
        if constexpr (SEQ)
          Hseq[((size_t)row*1024 + tt)*U + u] = __float2half(h);
        else
          if (tt == 1023) Hlast[(size_t)row*U + u] = h;
      }
      __syncthreads();
    }
  }
}

// ---------------- host launch ----------------
extern "C" void kernel_launch(void* const* d_in, const int* in_sizes, int n_in,
                              void* d_out, int out_size, void* d_ws, size_t ws_size,
                              hipStream_t stream)
{
  (void)in_sizes; (void)n_in; (void)out_size; (void)ws_size;
  const void*  x   = d_in[0];
  const float* Wk0 = (const float*)d_in[1];
  const float* Wr0 = (const float*)d_in[2];
  const float* b0  = (const float*)d_in[3];
  const float* Wk1 = (const float*)d_in[4];
  const float* Wr1 = (const float*)d_in[5];
  const float* b1  = (const float*)d_in[6];
  const float* Wko = (const float*)d_in[7];
  const float* Wro = (const float*)d_in[8];
  const float* bo  = (const float*)d_in[9];

  char* ws = (char*)d_ws;
  float*  masks = (float*)(ws + 256);                           // 1.5 MB
  __half* zin   = (__half*)(ws + 256 + 3*131072*4);             // 256 MB
  __half* h0    = (__half*)((char*)zin + (size_t)262144*512*2); // 64 MB
  __half* h1    = h0 + (size_t)262144*128;                      // 64 MB
  float*  out   = (float*)d_out;

  mask_kernel<<<1536, 256, 0, stream>>>(masks);

  // layer 0 (A = x, f32)
  gemm_mfma<128, MODE_F32><<<dim3(2048,4), 256, 0, stream>>>(x, Wk0, b0, masks, zin);
  rec2_kernel<128, true><<<256, 256, 0, stream>>>(zin, Wr0, h0, nullptr);
  // layer 1 (A = h0, f16 ours)
  gemm_mfma<128, MODE_F16><<<dim3(2048,4), 256, 0, stream>>>(h0, Wk1, b1, masks + 131072, zin);
  rec2_kernel<128, true><<<256, 256, 0, stream>>>(zin, Wr1, h1, nullptr);
  // layer 2 (output, U=64, last state only, f32 out)
  gemm_mfma<64, MODE_F16><<<dim3(2048,4), 256, 0, stream>>>(h1, Wko, bo, masks + 262144, zin);
  rec2_kernel<64, false><<<256, 128, 0, stream>>>(zin, Wro, nullptr, out);
}